// Round 4
// baseline (669.037 us; speedup 1.0000x reference)
//
#include <hip/hip_runtime.h>
#include <math.h>
#include <stdint.h>

// Problem constants (from reference)
constexpr int BATCH = 16384;
constexpr int KNEG  = 10;
constexpr int DIM   = 128;                        // 128 fp32 = 512 B per row
constexpr int SLOTS_PER_ITEM = 12;                // 10 negs + v + u
constexpr int NPAIR = BATCH * SLOTS_PER_ITEM;     // 196,608 gathered rows
constexpr int NBUCKET = 2048;                     // 512 table rows per bucket
constexpr int BUCKET_SHIFT = 9;                   // bucket = row >> 9

constexpr int ITEMS_PER_BLOCK = 8;                // compute kernel: 32 lanes/item
constexpr int NBLK_COMPUTE = BATCH / ITEMS_PER_BLOCK;   // 2048
constexpr int PAIRS_PER_BLOCK = 32;               // gather kernel: 4 rows per 32-lane group
constexpr int NBLK_GATHER = NPAIR / PAIRS_PER_BLOCK;    // 6144 (div by 8 for XCD swizzle)

// Workspace layout (byte offsets). Harness ws is ~2 GB; we use ~103 MB.
constexpr size_t WS_CNT   = 0;           // uint[NBUCKET]     bucket counts
constexpr size_t WS_CUR   = 16384;       // uint[NBUCKET]     scatter cursors (prefix sums)
constexpr size_t WS_PAIRS = 32768;       // uint64[NPAIR]     (row<<32)|slot, bucket-sorted
constexpr size_t WS_D     = 2097152;     // float[NPAIR*DIM]  dense gathered rows (100.7 MB)
constexpr size_t WS_PART  = 102760448;   // float[NBLK_COMPUTE] per-block partials

__device__ __forceinline__ float log_sigmoid(float x) {
    // stable: min(x,0) - log1p(exp(-|x|))
    return fminf(x, 0.0f) - log1pf(expf(-fabsf(x)));
}

// slot -> embedding row index. slot = item*12 + j; j<10: neg, 10: v, 11: u.
__device__ __forceinline__ int slot_row(int slot,
                                        const int* __restrict__ pos_v,
                                        const int* __restrict__ pos_u,
                                        const int* __restrict__ neg_v) {
    int item = slot / SLOTS_PER_ITEM;             // magic-mul div
    int j    = slot - item * SLOTS_PER_ITEM;
    if (j < KNEG) return neg_v[item * KNEG + j];
    return (j == KNEG) ? pos_v[item] : pos_u[item];
}

// K0: zero bucket counters (ws arrives poisoned every timed call).
__global__ void k0_zero(unsigned int* __restrict__ cnt) {
    int t = blockIdx.x * blockDim.x + threadIdx.x;
    if (t < NBUCKET) cnt[t] = 0u;
}

// K1: histogram pairs into buckets.
__global__ __launch_bounds__(256) void k1_count(
    const int* __restrict__ pos_v, const int* __restrict__ pos_u,
    const int* __restrict__ neg_v, unsigned int* __restrict__ cnt) {
    int slot = blockIdx.x * blockDim.x + threadIdx.x;   // grid exactly NPAIR
    int row  = slot_row(slot, pos_v, pos_u, neg_v);
    atomicAdd(&cnt[row >> BUCKET_SHIFT], 1u);
}

// K2: exclusive prefix sum of 2048 counts -> cursors. One 256-thread block.
__global__ __launch_bounds__(256) void k2_scan(
    const unsigned int* __restrict__ cnt, unsigned int* __restrict__ cur) {
    int t = threadIdx.x;
    unsigned int local[8];
    unsigned int s = 0;
#pragma unroll
    for (int i = 0; i < 8; ++i) { local[i] = cnt[t * 8 + i]; s += local[i]; }

    // inclusive shfl-scan of per-thread sums within each 64-lane wave
    unsigned int v = s;
#pragma unroll
    for (int d = 1; d < 64; d <<= 1) {
        unsigned int n = __shfl_up(v, d, 64);
        if ((t & 63) >= d) v += n;
    }
    __shared__ unsigned int wsum[4];
    if ((t & 63) == 63) wsum[t >> 6] = v;
    __syncthreads();
    unsigned int woff = 0;
    for (int w = 0; w < (t >> 6); ++w) woff += wsum[w];
    unsigned int run = woff + v - s;              // exclusive prefix for this thread
#pragma unroll
    for (int i = 0; i < 8; ++i) { cur[t * 8 + i] = run; run += local[i]; }
}

// K3: scatter (row,slot) records into bucket-sorted order.
__global__ __launch_bounds__(256) void k3_scatter(
    const int* __restrict__ pos_v, const int* __restrict__ pos_u,
    const int* __restrict__ neg_v, unsigned int* __restrict__ cur,
    uint64_t* __restrict__ pairs) {
    int slot = blockIdx.x * blockDim.x + threadIdx.x;
    int row  = slot_row(slot, pos_v, pos_u, neg_v);
    unsigned int p = atomicAdd(&cur[row >> BUCKET_SHIFT], 1u);
    pairs[p] = ((uint64_t)(unsigned int)row << 32) | (unsigned int)slot;
}

// K4: bucket-ordered gather. Reads emb with page/row locality, scatter-writes
// dense rows into D[slot]. 4 rows in flight per 32-lane group for MLP.
__global__ __launch_bounds__(256) void k4_gather(
    const uint64_t* __restrict__ pairs, const float* __restrict__ emb,
    float* __restrict__ D) {
    int bid = blockIdx.x;
    // XCD-chunked swizzle: each XCD takes a contiguous 1/8 of sorted pairs.
    constexpr int q = NBLK_GATHER / 8;
    int swz = (bid % 8) * q + bid / 8;
    int lane = threadIdx.x & 31;
    int grp  = threadIdx.x >> 5;                  // 0..7
    int base = swz * PAIRS_PER_BLOCK;

    float4 r[4];
    uint32_t slot[4];
#pragma unroll
    for (int i = 0; i < 4; ++i) {                 // issue all reads first (MLP)
        uint64_t p = pairs[base + grp + i * 8];
        slot[i] = (uint32_t)p;
        const float4* src = (const float4*)(emb + (size_t)(p >> 32) * DIM);
        r[i] = src[lane];
    }
#pragma unroll
    for (int i = 0; i < 4; ++i) {                 // fire-and-forget scatter writes
        float4* dst = (float4*)(D + (size_t)slot[i] * DIM);
        dst[lane] = r[i];
    }
}

// K5: streaming compute. Identical arithmetic/order to the verified kernel,
// but rows come from dense D (sequential 6 KB per item).
__global__ __launch_bounds__(256, 4) void k5_compute(
    const float* __restrict__ D, const float* __restrict__ weights,
    float* __restrict__ partials) {
    const int tid  = threadIdx.x;
    const int lane = tid & 31;
    const int item = tid >> 5;
    const int b    = blockIdx.x * ITEMS_PER_BLOCK + item;
    const size_t sbase = (size_t)b * SLOTS_PER_ITEM * DIM;

    const float4* vrow = (const float4*)(D + sbase + (size_t)KNEG * DIM);       // slot 12b+10
    const float4* urow = (const float4*)(D + sbase + (size_t)(KNEG + 1) * DIM); // slot 12b+11
    const float4 v = vrow[lane];
    const float4 u = urow[lane];

    float dots[KNEG + 1];
    dots[KNEG] = v.x * u.x + v.y * u.y + v.z * u.z + v.w * u.w;
#pragma unroll
    for (int k = 0; k < KNEG; ++k) {
        const float4 n = ((const float4*)(D + sbase + (size_t)k * DIM))[lane];
        dots[k] = v.x * n.x + v.y * n.y + v.z * n.z + v.w * n.w;
    }
#pragma unroll
    for (int k = 0; k <= KNEG; ++k) {
#pragma unroll
        for (int off = 16; off; off >>= 1)
            dots[k] += __shfl_down(dots[k], off, 32);
    }

    __shared__ float partial[ITEMS_PER_BLOCK];
    if (lane == 0) {
        float s = log_sigmoid(dots[KNEG]);
#pragma unroll
        for (int k = 0; k < KNEG; ++k)
            s += log_sigmoid(-dots[k]);
        partial[item] = weights[b] * s;
    }
    __syncthreads();
    if (tid == 0) {
        float acc = 0.0f;
#pragma unroll
        for (int i = 0; i < ITEMS_PER_BLOCK; ++i) acc += partial[i];
        partials[blockIdx.x] = acc;
    }
}

// K6: fold 2048 partials, overwrite d_out with final value. Poison-immune.
__global__ __launch_bounds__(256) void k6_reduce(
    const float* __restrict__ partials, float* __restrict__ out) {
    const int tid = threadIdx.x;
    float acc = 0.0f;
#pragma unroll
    for (int i = 0; i < NBLK_COMPUTE / 256; ++i)
        acc += partials[tid + i * 256];
#pragma unroll
    for (int off = 32; off; off >>= 1)
        acc += __shfl_down(acc, off, 64);
    __shared__ float sp[4];
    if ((tid & 63) == 0) sp[tid >> 6] = acc;
    __syncthreads();
    if (tid == 0)
        out[0] = -(sp[0] + sp[1] + sp[2] + sp[3]);
}

extern "C" void kernel_launch(void* const* d_in, const int* in_sizes, int n_in,
                              void* d_out, int out_size, void* d_ws, size_t ws_size,
                              hipStream_t stream) {
    const int*   pos_v   = (const int*)d_in[0];
    const int*   pos_u   = (const int*)d_in[1];
    const int*   neg_v   = (const int*)d_in[2];
    const float* weights = (const float*)d_in[3];
    const float* emb     = (const float*)d_in[4];
    float*       out     = (float*)d_out;
    char*        ws      = (char*)d_ws;

    unsigned int* cnt   = (unsigned int*)(ws + WS_CNT);
    unsigned int* cur   = (unsigned int*)(ws + WS_CUR);
    uint64_t*     pairs = (uint64_t*)(ws + WS_PAIRS);
    float*        D     = (float*)(ws + WS_D);
    float*        part  = (float*)(ws + WS_PART);

    k0_zero   <<<dim3((NBUCKET + 255) / 256), 256, 0, stream>>>(cnt);
    k1_count  <<<dim3(NPAIR / 256), 256, 0, stream>>>(pos_v, pos_u, neg_v, cnt);
    k2_scan   <<<dim3(1), 256, 0, stream>>>(cnt, cur);
    k3_scatter<<<dim3(NPAIR / 256), 256, 0, stream>>>(pos_v, pos_u, neg_v, cur, pairs);
    k4_gather <<<dim3(NBLK_GATHER), 256, 0, stream>>>(pairs, emb, D);
    k5_compute<<<dim3(NBLK_COMPUTE), 256, 0, stream>>>(D, weights, part);
    k6_reduce <<<dim3(1), 256, 0, stream>>>(part, out);
}